// Round 5
// baseline (488.290 us; speedup 1.0000x reference)
//
#include <hip/hip_runtime.h>
#include <stdint.h>

typedef __bf16 bf16_t;
typedef __attribute__((ext_vector_type(8))) __bf16 bfv8;
typedef __attribute__((ext_vector_type(4))) __bf16 bfv4;
typedef __attribute__((ext_vector_type(4))) float f32x4;

constexpr int BATCH = 2, SEQ = 8192, DIM = 1024, NH = 16, HDIM = 64, FDIM = 256;
constexpr int MROWS = BATCH * SEQ;  // 16384
constexpr int NCHUNK = 8;           // kv s-chunks (1024 s each)

__device__ __forceinline__ f32x4 mfma_bf16(bfv8 a, bfv8 b, f32x4 c) {
  return __builtin_amdgcn_mfma_f32_16x16x32_bf16(a, b, c, 0, 0, 0);
}

// ---- async global->LDS 16B (LDS dst wave-uniform base + lane*16) ----
__device__ __forceinline__ void gload_lds16(const bf16_t* g, bf16_t* lds) {
  auto const* gp = reinterpret_cast<const __attribute__((address_space(1))) uint32_t*>(
      reinterpret_cast<uintptr_t>(g));
  auto* lp = reinterpret_cast<__attribute__((address_space(3))) uint32_t*>(
      reinterpret_cast<uintptr_t>(lds));
  __builtin_amdgcn_global_load_lds(gp, lp, 16, 0, 0);
}

// ================= 256x256 8-phase GEMM (C = A @ W^T), bf16 in =================
// 512 thr = 8 waves (2M x 4N); wave tile 128x64; BK=64; LDS 128KB double-buffered.
// Staged "halves" are quadrant-aligned: A-half mq = rows {wr*128+mq*64..+63} for both wr;
// B-half nq = N-rows {wc*64+nq*32..+31} for all wc. Each phase = one C-quadrant (16 MFMA),
// consumes exactly (A-half mq, B-half nq); stages one future half-tile; counted vmcnt(4)
// at phases 4/8 only (tile t+1 / t+2 landing verified there; see lifetime analysis).

template <int MQ, int NQ>
__device__ __forceinline__ void quad16(f32x4 (&acc)[8][4], bfv8 (&af)[4][2], bfv8 (&bg)[2][2]) {
  __builtin_amdgcn_s_setprio(1);
#pragma unroll
  for (int m = 0; m < 4; ++m)
#pragma unroll
    for (int n = 0; n < 2; ++n)
#pragma unroll
      for (int kk = 0; kk < 2; ++kk)
        acc[MQ * 4 + m][NQ * 2 + n] = mfma_bf16(af[m][kk], bg[n][kk], acc[MQ * 4 + m][NQ * 2 + n]);
  __builtin_amdgcn_s_setprio(0);
}

template <typename CT, int NZ>
__global__ __launch_bounds__(512, 2) void gemm8p(const bf16_t* __restrict__ A,
                                                 const bf16_t* __restrict__ Wall,
                                                 CT* __restrict__ C0, CT* __restrict__ C1,
                                                 CT* __restrict__ C2) {
  extern __shared__ bf16_t lds[];  // [buf2][tensor2][half2][128*64] = 128KB
  constexpr int NBLK = 64 * 4 * NZ;
  int lin = blockIdx.x;
  int swz = (lin & 7) * (NBLK / 8) + (lin >> 3);  // XCD-contiguous chunks (NBLK%8==0)
  int z = (NZ == 3) ? (swz >> 8) : 0;
  int rem = swz & 255;
  int bx = rem & 63, by = rem >> 6;
  const bf16_t* Wm = Wall + (size_t)z * DIM * DIM;
  CT* C = (z == 0) ? C0 : ((z == 1) ? C1 : C2);
  int brow = bx * 256, bcol = by * 256;
  const bf16_t* Abase = A + (size_t)brow * DIM;
  const bf16_t* Bbase = Wm + (size_t)bcol * DIM;

  int tid = threadIdx.x;
  int lane = tid & 63, wid = tid >> 6;
  int lr = lane & 15, lg = lane >> 4;
  int wr = wid >> 2, wc = wid & 3;

  // staging constants: chunk rows (wid*2+j)*8 + lane>>3; source slot xor by LDS row&7
  int gslot = (lane & 7) ^ (lane >> 3);
  int idx0 = (wid * 2 + 0) * 8 + (lane >> 3);
  int idx1 = (wid * 2 + 1) * 8 + (lane >> 3);

  auto reg = [&](int buf, int tensor, int half) -> bf16_t* {
    return lds + (((buf * 2 + tensor) * 2 + half) << 13);
  };
  auto STAGE_A = [&](int buf, int h, int k0) {
    bf16_t* dst = reg(buf, 0, h);
    {
      int grow = ((idx0 >> 6) * 128) + h * 64 + (idx0 & 63);
      gload_lds16(Abase + (size_t)grow * DIM + k0 + gslot * 8, dst + (wid * 2 + 0) * 512);
    }
    {
      int grow = ((idx1 >> 6) * 128) + h * 64 + (idx1 & 63);
      gload_lds16(Abase + (size_t)grow * DIM + k0 + gslot * 8, dst + (wid * 2 + 1) * 512);
    }
  };
  auto STAGE_B = [&](int buf, int h, int k0) {
    bf16_t* dst = reg(buf, 1, h);
    {
      int grow = ((idx0 >> 5) * 64) + h * 32 + (idx0 & 31);
      gload_lds16(Bbase + (size_t)grow * DIM + k0 + gslot * 8, dst + (wid * 2 + 0) * 512);
    }
    {
      int grow = ((idx1 >> 5) * 64) + h * 32 + (idx1 & 31);
      gload_lds16(Bbase + (size_t)grow * DIM + k0 + gslot * 8, dst + (wid * 2 + 1) * 512);
    }
  };

  f32x4 acc[8][4] = {};
  bfv8 af[4][2], bg0[2][2], bg1[2][2];

  auto LDA = [&](int buf, int mq) {
#pragma unroll
    for (int m = 0; m < 4; ++m)
#pragma unroll
      for (int kk = 0; kk < 2; ++kk) {
        int row = wr * 64 + m * 16 + lr;
        af[m][kk] = *reinterpret_cast<const bfv8*>(reg(buf, 0, mq) + row * 64 +
                                                   (((kk * 4 + lg) ^ (lr & 7)) * 8));
      }
  };
  auto LDB = [&](bfv8(&bg)[2][2], int buf, int nq) {
#pragma unroll
    for (int n = 0; n < 2; ++n)
#pragma unroll
      for (int kk = 0; kk < 2; ++kk) {
        int row = wc * 32 + n * 16 + lr;
        bg[n][kk] = *reinterpret_cast<const bfv8*>(reg(buf, 1, nq) + row * 64 +
                                                   (((kk * 4 + lg) ^ (lr & 7)) * 8));
      }
  };

#define BAR() __builtin_amdgcn_s_barrier()
#define VM4() asm volatile("s_waitcnt vmcnt(4)" ::: "memory")
#define VM0() asm volatile("s_waitcnt vmcnt(0)" ::: "memory")
#define SCHED0() __builtin_amdgcn_sched_barrier(0)

  // prologue: tile0 (all 4 halves), then tile1 A0,B1; vmcnt(4) -> tile0 landed
  STAGE_A(0, 0, 0); STAGE_B(0, 1, 0); STAGE_A(0, 1, 0); STAGE_B(0, 0, 0);
  STAGE_A(1, 0, 64); STAGE_B(1, 1, 64);
  VM4(); BAR(); SCHED0();

  for (int I = 0; I < 8; ++I) {        // tiles t=2I (buf0), t+1 (buf1)
    const bool full = (I < 7);
    const int k1 = I * 128 + 64, k2 = I * 128 + 128, k3 = I * 128 + 192;
    // P1: quad(0,0) tile t; stage A1(t+1)
    LDA(0, 0); LDB(bg0, 0, 0); STAGE_A(1, 1, k1);
    BAR(); quad16<0, 0>(acc, af, bg0); BAR();
    // P2: quad(0,1); stage B0(t+1)
    LDB(bg1, 0, 1); STAGE_B(1, 0, k1);
    BAR(); quad16<0, 1>(acc, af, bg1); BAR();
    // P3: quad(1,1); stage A0(t+2)
    LDA(0, 1);
    if (full) STAGE_A(0, 0, k2);
    BAR(); quad16<1, 1>(acc, af, bg1); BAR();
    // P4: quad(1,0); stage B1(t+2); verify tile t+1 landed
    if (full) STAGE_B(0, 1, k2);
    BAR(); quad16<1, 0>(acc, af, bg0);
    if (full) { VM4(); } else { VM0(); }
    BAR(); SCHED0();
    // P5: quad(0,0) tile t+1; stage A1(t+2)
    LDA(1, 0); LDB(bg0, 1, 0);
    if (full) STAGE_A(0, 1, k2);
    BAR(); quad16<0, 0>(acc, af, bg0); BAR();
    // P6: quad(0,1); stage B0(t+2)
    LDB(bg1, 1, 1);
    if (full) STAGE_B(0, 0, k2);
    BAR(); quad16<0, 1>(acc, af, bg1); BAR();
    // P7: quad(1,1); stage A0(t+3)
    LDA(1, 1);
    if (full) STAGE_A(1, 0, k3);
    BAR(); quad16<1, 1>(acc, af, bg1); BAR();
    // P8: quad(1,0); stage B1(t+3); verify tile t+2 landed
    if (full) STAGE_B(1, 1, k3);
    BAR(); quad16<1, 0>(acc, af, bg0);
    if (full) { VM4(); }
    BAR(); SCHED0();
  }
#undef BAR
#undef VM4
#undef VM0
#undef SCHED0

#pragma unroll
  for (int mi = 0; mi < 8; ++mi) {
    int r = brow + wr * 128 + (mi >> 2) * 64 + (mi & 3) * 16 + lg * 4;
#pragma unroll
    for (int ni = 0; ni < 4; ++ni) {
      int c = bcol + wc * 64 + (ni >> 1) * 32 + (ni & 1) * 16 + lr;
#pragma unroll
      for (int q = 0; q < 4; ++q) C[(size_t)(r + q) * DIM + c] = (CT)acc[mi][ni][q];
    }
  }
}

// ---------------- fp32 -> bf16 convert (vectorized x4) ----------------
__global__ __launch_bounds__(256) void cvt_kernel(const float* __restrict__ in,
                                                  bf16_t* __restrict__ out, int n4) {
  int i = blockIdx.x * blockDim.x + threadIdx.x;
  int stride = gridDim.x * blockDim.x;
  for (; i < n4; i += stride) {
    float4 v = reinterpret_cast<const float4*>(in)[i];
    bfv4 o = {(__bf16)v.x, (__bf16)v.y, (__bf16)v.z, (__bf16)v.w};
    reinterpret_cast<bfv4*>(out)[i] = o;
  }
}

// ------- fused featk+kv: kv_part[chunk][bh][n=80][f=256] (n=64 is k_sum) -------
__global__ __launch_bounds__(256) void kv_fused(const bf16_t* __restrict__ Kb,
                                                const bf16_t* __restrict__ Vb,
                                                const bf16_t* __restrict__ Wf,
                                                float* __restrict__ kv_part) {
  __shared__ bf16_t kf_lds[256 * 36];
  __shared__ bf16_t vt[80 * 36];
  int chunk = blockIdx.x, bh = blockIdx.y;
  int b = bh >> 4, h = bh & 15;
  int lane = threadIdx.x & 63, wid = threadIdx.x >> 6;
  int lr = lane & 15, lg = lane >> 4;
  int f0 = wid * 64;
  for (int i = threadIdx.x; i < 16 * 36; i += 256) {
    int n = i / 36, s = i - n * 36;
    vt[(64 + n) * 36 + s] = (n == 0) ? (__bf16)1.0f : (__bf16)0.0f;
  }
  bfv8 wf[4][2];
#pragma unroll
  for (int ft = 0; ft < 4; ++ft)
#pragma unroll
    for (int kk = 0; kk < 2; ++kk)
      wf[ft][kk] = *reinterpret_cast<const bfv8*>(Wf + (size_t)(f0 + ft * 16 + lr) * HDIM + kk * 32 + lg * 8);
  f32x4 acc[4][5] = {};
  int si = threadIdx.x >> 3, c8 = threadIdx.x & 7;
  const bf16_t* Kbase = Kb + (size_t)b * SEQ * DIM + h * HDIM;
  const bf16_t* Vbase = Vb + (size_t)b * SEQ * DIM + h * HDIM;
  for (int it = 0; it < 32; ++it) {
    int sb = chunk * 1024 + it * 32;
    bfv8 vv = *reinterpret_cast<const bfv8*>(Vbase + (size_t)(sb + si) * DIM + c8 * 8);
    bfv8 krg[2][2];
#pragma unroll
    for (int st = 0; st < 2; ++st)
#pragma unroll
      for (int kk = 0; kk < 2; ++kk)
        krg[st][kk] = *reinterpret_cast<const bfv8*>(Kbase + (size_t)(sb + st * 16 + lr) * DIM + kk * 32 + lg * 8);
    f32x4 ckf[4][2] = {};
#pragma unroll
    for (int ft = 0; ft < 4; ++ft)
#pragma unroll
      for (int st = 0; st < 2; ++st)
#pragma unroll
        for (int kk = 0; kk < 2; ++kk) ckf[ft][st] = mfma_bf16(wf[ft][kk], krg[st][kk], ckf[ft][st]);
    __syncthreads();
#pragma unroll
    for (int j = 0; j < 8; ++j) vt[(c8 * 8 + j) * 36 + si] = vv[j];
#pragma unroll
    for (int ft = 0; ft < 4; ++ft)
#pragma unroll
      for (int st = 0; st < 2; ++st)
#pragma unroll
        for (int q = 0; q < 4; ++q) {
          float x = ckf[ft][st][q];
          x = (x > 0.0f) ? (x + 1.0f) : __expf(x);
          kf_lds[(size_t)(f0 + ft * 16 + lg * 4 + q) * 36 + st * 16 + lr] = (__bf16)x;
        }
    __syncthreads();
    bfv8 af[4], bg[5];
#pragma unroll
    for (int ft = 0; ft < 4; ++ft)
      af[ft] = *reinterpret_cast<const bfv8*>(&kf_lds[(size_t)(f0 + ft * 16 + lr) * 36 + lg * 8]);
#pragma unroll
    for (int nt = 0; nt < 5; ++nt)
      bg[nt] = *reinterpret_cast<const bfv8*>(&vt[(size_t)(nt * 16 + lr) * 36 + lg * 8]);
#pragma unroll
    for (int ft = 0; ft < 4; ++ft)
#pragma unroll
      for (int nt = 0; nt < 5; ++nt) acc[ft][nt] = mfma_bf16(af[ft], bg[nt], acc[ft][nt]);
  }
  float* outb = kv_part + ((size_t)chunk * 32 + bh) * 80 * FDIM;
#pragma unroll
  for (int ft = 0; ft < 4; ++ft)
#pragma unroll
    for (int nt = 0; nt < 5; ++nt)
      *reinterpret_cast<f32x4*>(&outb[(size_t)(nt * 16 + lr) * FDIM + f0 + ft * 16 + lg * 4]) = acc[ft][nt];
}

// ---------------- reduce NCHUNK partials -> kvT bf16 [bh][n=80][f=256] ----------------
__global__ __launch_bounds__(256) void kv_reduce(const float* __restrict__ part,
                                                 bf16_t* __restrict__ kvT) {
  int i = blockIdx.x * 256 + threadIdx.x;
  float s = 0.0f;
#pragma unroll
  for (int c = 0; c < NCHUNK; ++c) s += part[(size_t)c * 655360 + i];
  kvT[i] = (__bf16)s;
}

// ------- fused featq+readout: outp = (qf @ kv) / (qf . ksum + 1e-6), grid (M/64, NH) -------
__global__ __launch_bounds__(256) void attn_fused(const bf16_t* __restrict__ Qb,
                                                  const bf16_t* __restrict__ Wf,
                                                  const bf16_t* __restrict__ kvT,
                                                  bf16_t* __restrict__ outp) {
  __shared__ bf16_t qf_lds[64 * 264];
  int rb = blockIdx.x, h = blockIdx.y;
  int row0 = rb * 64;
  int bh = (row0 >> 13) * NH + h;
  int lane = threadIdx.x & 63, wid = threadIdx.x >> 6;
  int lr = lane & 15, lg = lane >> 4;
  int f0 = wid * 64;
  bfv8 qa[4][2], wfb[4][2];
#pragma unroll
  for (int t = 0; t < 4; ++t)
#pragma unroll
    for (int kk = 0; kk < 2; ++kk) {
      qa[t][kk] = *reinterpret_cast<const bfv8*>(Qb + (size_t)(row0 + t * 16 + lr) * DIM + h * HDIM + kk * 32 + lg * 8);
      wfb[t][kk] = *reinterpret_cast<const bfv8*>(Wf + (size_t)(f0 + t * 16 + lr) * HDIM + kk * 32 + lg * 8);
    }
  f32x4 cq[4][4] = {};
#pragma unroll
  for (int rt = 0; rt < 4; ++rt)
#pragma unroll
    for (int ft = 0; ft < 4; ++ft)
#pragma unroll
      for (int kk = 0; kk < 2; ++kk) cq[rt][ft] = mfma_bf16(qa[rt][kk], wfb[ft][kk], cq[rt][ft]);
#pragma unroll
  for (int rt = 0; rt < 4; ++rt)
#pragma unroll
    for (int ft = 0; ft < 4; ++ft)
#pragma unroll
      for (int q = 0; q < 4; ++q) {
        float x = cq[rt][ft][q];
        x = (x > 0.0f) ? (x + 1.0f) : __expf(x);
        qf_lds[(size_t)(rt * 16 + lg * 4 + q) * 264 + f0 + ft * 16 + lr] = (__bf16)x;
      }
  __syncthreads();
  f32x4 acc[5] = {};
  for (int ks = 0; ks < 8; ++ks) {
    bfv8 a = *reinterpret_cast<const bfv8*>(&qf_lds[(size_t)(wid * 16 + lr) * 264 + ks * 32 + lg * 8]);
#pragma unroll
    for (int nt = 0; nt < 5; ++nt) {
      bfv8 bg = *reinterpret_cast<const bfv8*>(kvT + ((size_t)bh * 80 + nt * 16 + lr) * FDIM + ks * 32 + lg * 8);
      acc[nt] = mfma_bf16(a, bg, acc[nt]);
    }
  }
#pragma unroll
  for (int q = 0; q < 4; ++q) {
    float nrm = __shfl(acc[4][q], (lane & 48)) + 1e-6f;
    int r = row0 + wid * 16 + lg * 4 + q;
#pragma unroll
    for (int nt = 0; nt < 4; ++nt)
      outp[(size_t)r * DIM + h * HDIM + nt * 16 + lr] = (__bf16)(acc[nt][q] / nrm);
  }
}

extern "C" void kernel_launch(void* const* d_in, const int* in_sizes, int n_in,
                              void* d_out, int out_size, void* d_ws, size_t ws_size,
                              hipStream_t stream) {
  const float* X  = (const float*)d_in[0];
  const float* Wq = (const float*)d_in[1];
  const float* Wk = (const float*)d_in[2];
  const float* Wv = (const float*)d_in[3];
  const float* Wo = (const float*)d_in[4];
  const float* Wf = (const float*)d_in[5];
  float* out = (float*)d_out;
  char* ws = (char*)d_ws;
  const size_t MB = 1ull << 20;
  if (ws_size < 75 * MB) return;

  bf16_t* Xb  = (bf16_t*)(ws + 0 * MB);    // 32MB; dead after gemm_qkv
  bf16_t* Qb  = (bf16_t*)(ws + 32 * MB);   // 32MB; live until attn_fused
  bf16_t* W3  = (bf16_t*)(ws + 64 * MB);   // Wq,Wk,Wv bf16 contiguous (6MB)
  bf16_t* Wob = (bf16_t*)(ws + 70 * MB);   // 2MB
  bf16_t* Wfb = (bf16_t*)(ws + 72 * MB);   // 32KB
  bf16_t* kvT = (bf16_t*)(ws + 73 * MB);   // 1.31MB
  float* kv_part = (float*)(ws + 0 * MB);  // 21MB over dead Xb
  bf16_t* outp = (bf16_t*)(ws + 0 * MB);   // 32MB over dead kv_part/Xb
  bf16_t* Kb = (bf16_t*)d_out;             // 32MB scratch in d_out
  bf16_t* Vb = Kb + (size_t)MROWS * DIM;   // 32MB scratch in d_out

  cvt_kernel<<<4096, 256, 0, stream>>>(X, Xb, 16777216 / 4);
  cvt_kernel<<<1024, 256, 0, stream>>>(Wq, W3, 1048576 / 4);
  cvt_kernel<<<1024, 256, 0, stream>>>(Wk, W3 + 1048576, 1048576 / 4);
  cvt_kernel<<<1024, 256, 0, stream>>>(Wv, W3 + 2097152, 1048576 / 4);
  cvt_kernel<<<1024, 256, 0, stream>>>(Wo, Wob, 1048576 / 4);
  cvt_kernel<<<16, 256, 0, stream>>>(Wf, Wfb, 16384 / 4);

  gemm8p<bf16_t, 3><<<768, 512, 131072, stream>>>(Xb, W3, Qb, Kb, Vb);
  kv_fused<<<dim3(NCHUNK, 32), 256, 0, stream>>>(Kb, Vb, Wfb, kv_part);
  kv_reduce<<<2560, 256, 0, stream>>>(kv_part, kvT);
  attn_fused<<<dim3(256, NH), 256, 0, stream>>>(Qb, Wfb, kvT, outp);
  gemm8p<float, 1><<<256, 512, 131072, stream>>>(outp, Wob, out, out, out);
}

// Round 6
// 357.790 us; speedup vs baseline: 1.3647x; 1.3647x over previous
//
#include <hip/hip_runtime.h>
#include <stdint.h>

typedef __bf16 bf16_t;
typedef __attribute__((ext_vector_type(8))) __bf16 bfv8;
typedef __attribute__((ext_vector_type(4))) __bf16 bfv4;
typedef __attribute__((ext_vector_type(4))) float f32x4;

constexpr int BATCH = 2, SEQ = 8192, DIM = 1024, NH = 16, HDIM = 64, FDIM = 256;
constexpr int MROWS = BATCH * SEQ;  // 16384
constexpr int NCHUNK = 16;          // kv s-chunks (512 s each)
constexpr int KV_NIT = (SEQ / NCHUNK) / 32;  // 16 iterations of 32 s

__device__ __forceinline__ f32x4 mfma_bf16(bfv8 a, bfv8 b, f32x4 c) {
  return __builtin_amdgcn_mfma_f32_16x16x32_bf16(a, b, c, 0, 0, 0);
}

// ---- async global->LDS 16B (LDS dst wave-uniform base + lane*16) ----
__device__ __forceinline__ void gload_lds16(const bf16_t* g, bf16_t* lds) {
  auto const* gp = reinterpret_cast<const __attribute__((address_space(1))) uint32_t*>(
      reinterpret_cast<uintptr_t>(g));
  auto* lp = reinterpret_cast<__attribute__((address_space(3))) uint32_t*>(
      reinterpret_cast<uintptr_t>(lds));
  __builtin_amdgcn_global_load_lds(gp, lp, 16, 0, 0);
}

// ---- stage a 128x64 bf16 tile into LDS (linear [128][64]), xor-swizzled source ----
__device__ __forceinline__ void stage128x64(const bf16_t* g_base, int k0,
                                            bf16_t* lds, int wid, int lane) {
#pragma unroll
  for (int j = 0; j < 4; ++j) {
    int r0 = (wid * 4 + j) * 8;                 // wave-uniform
    int g_row = r0 + (lane >> 3);
    int g_slot = (lane & 7) ^ (g_row & 7);
    const bf16_t* src = g_base + (size_t)g_row * DIM + k0 + g_slot * 8;
    gload_lds16(src, lds + r0 * 64);
  }
}

// ---------------- fp32 -> bf16 convert: X (grid-stride) ----------------
__global__ __launch_bounds__(256) void cvt_kernel(const float* __restrict__ in,
                                                  bf16_t* __restrict__ out, int n4) {
  int i = blockIdx.x * blockDim.x + threadIdx.x;
  int stride = gridDim.x * blockDim.x;
  for (; i < n4; i += stride) {
    float4 v = reinterpret_cast<const float4*>(in)[i];
    bfv4 o = {(__bf16)v.x, (__bf16)v.y, (__bf16)v.z, (__bf16)v.w};
    reinterpret_cast<bfv4*>(out)[i] = o;
  }
}

// ---------------- fused weight converts: Wq,Wk,Wv -> W3; Wo -> Wob; Wf -> Wfb ---------
// total float4s = 3*262144 + 262144 + 4096 = 1052672; grid 4112 x 256
__global__ __launch_bounds__(256) void cvt_weights(const float* __restrict__ Wq,
                                                   const float* __restrict__ Wk,
                                                   const float* __restrict__ Wv,
                                                   const float* __restrict__ Wo,
                                                   const float* __restrict__ Wf,
                                                   bf16_t* __restrict__ W3,
                                                   bf16_t* __restrict__ Wob,
                                                   bf16_t* __restrict__ Wfb) {
  int i = blockIdx.x * 256 + threadIdx.x;
  const float* src;
  bf16_t* dst;
  int off;
  if (i < 786432) {
    int seg = i >> 18;
    off = i & 262143;
    src = (seg == 0) ? Wq : ((seg == 1) ? Wk : Wv);
    dst = W3 + (size_t)seg * 1048576;
  } else if (i < 1048576) {
    off = i - 786432;
    src = Wo;
    dst = Wob;
  } else {
    off = i - 1048576;
    src = Wf;
    dst = Wfb;
  }
  float4 v = reinterpret_cast<const float4*>(src)[off];
  bfv4 o = {(__bf16)v.x, (__bf16)v.y, (__bf16)v.z, (__bf16)v.w};
  reinterpret_cast<bfv4*>(dst)[off] = o;
}

// ---------------- Q/K/V projection: C = X @ W^T (bf16 out), LDS-staged ----------------
__global__ __launch_bounds__(256) void gemm_qkv(const bf16_t* __restrict__ A,
                                                const bf16_t* __restrict__ Wall,
                                                bf16_t* __restrict__ Q,
                                                bf16_t* __restrict__ K,
                                                bf16_t* __restrict__ V) {
  __shared__ bf16_t As[128 * 64];
  __shared__ bf16_t Bs[128 * 64];
  int z = blockIdx.z;
  const bf16_t* Wm = Wall + (size_t)z * (DIM * DIM);
  bf16_t* C = (z == 0) ? Q : ((z == 1) ? K : V);
  int lane = threadIdx.x & 63, wid = threadIdx.x >> 6;
  int lr = lane & 15, lg = lane >> 4;
  int wr = wid >> 1, wc = wid & 1;
  int brow = blockIdx.x * 128, bcol = blockIdx.y * 128;
  const bf16_t* Ab = A + (size_t)brow * DIM;
  const bf16_t* Bb = Wm + (size_t)bcol * DIM;
  f32x4 acc[4][4] = {};
  for (int ks = 0; ks < DIM / 64; ++ks) {
    stage128x64(Ab, ks * 64, As, wid, lane);
    stage128x64(Bb, ks * 64, Bs, wid, lane);
    __syncthreads();
#pragma unroll
    for (int kk = 0; kk < 2; ++kk) {
      bfv8 af[4], bg[4];
#pragma unroll
      for (int t = 0; t < 4; ++t) {
        int ar = wr * 64 + t * 16 + lr;
        af[t] = *reinterpret_cast<const bfv8*>(&As[ar * 64 + (((kk * 4 + lg) ^ (ar & 7)) * 8)]);
        int br = wc * 64 + t * 16 + lr;
        bg[t] = *reinterpret_cast<const bfv8*>(&Bs[br * 64 + (((kk * 4 + lg) ^ (br & 7)) * 8)]);
      }
#pragma unroll
      for (int i = 0; i < 4; ++i)
#pragma unroll
        for (int j = 0; j < 4; ++j) acc[i][j] = mfma_bf16(af[i], bg[j], acc[i][j]);
    }
    __syncthreads();
  }
#pragma unroll
  for (int i = 0; i < 4; ++i) {
    int r = brow + wr * 64 + i * 16 + lg * 4;
#pragma unroll
    for (int j = 0; j < 4; ++j) {
      int c = bcol + wc * 64 + j * 16 + lr;
#pragma unroll
      for (int q = 0; q < 4; ++q) C[(size_t)(r + q) * DIM + c] = (__bf16)acc[i][j][q];
    }
  }
}

// ---------------- final: d_out = out_pre @ Wo^T (fp32 out), LDS-staged ----------------
__global__ __launch_bounds__(256) void gemm_final(const bf16_t* __restrict__ A,
                                                  const bf16_t* __restrict__ W,
                                                  float* __restrict__ C) {
  __shared__ bf16_t As[128 * 64];
  __shared__ bf16_t Bs[128 * 64];
  int lane = threadIdx.x & 63, wid = threadIdx.x >> 6;
  int lr = lane & 15, lg = lane >> 4;
  int wr = wid >> 1, wc = wid & 1;
  int brow = blockIdx.x * 128, bcol = blockIdx.y * 128;
  const bf16_t* Ab = A + (size_t)brow * DIM;
  const bf16_t* Bb = W + (size_t)bcol * DIM;
  f32x4 acc[4][4] = {};
  for (int ks = 0; ks < DIM / 64; ++ks) {
    stage128x64(Ab, ks * 64, As, wid, lane);
    stage128x64(Bb, ks * 64, Bs, wid, lane);
    __syncthreads();
#pragma unroll
    for (int kk = 0; kk < 2; ++kk) {
      bfv8 af[4], bg[4];
#pragma unroll
      for (int t = 0; t < 4; ++t) {
        int ar = wr * 64 + t * 16 + lr;
        af[t] = *reinterpret_cast<const bfv8*>(&As[ar * 64 + (((kk * 4 + lg) ^ (ar & 7)) * 8)]);
        int br = wc * 64 + t * 16 + lr;
        bg[t] = *reinterpret_cast<const bfv8*>(&Bs[br * 64 + (((kk * 4 + lg) ^ (br & 7)) * 8)]);
      }
#pragma unroll
      for (int i = 0; i < 4; ++i)
#pragma unroll
        for (int j = 0; j < 4; ++j) acc[i][j] = mfma_bf16(af[i], bg[j], acc[i][j]);
    }
    __syncthreads();
  }
#pragma unroll
  for (int i = 0; i < 4; ++i) {
    int r = brow + wr * 64 + i * 16 + lg * 4;
#pragma unroll
    for (int j = 0; j < 4; ++j) {
      int c = bcol + wc * 64 + j * 16 + lr;
#pragma unroll
      for (int q = 0; q < 4; ++q) C[(size_t)(r + q) * DIM + c] = acc[i][j][q];
    }
  }
}

// ------- fused featk+kv v2: 1 raw barrier/iter, wave-private kf, dbuf vt, reg prefetch ----
// kv_part[chunk][bh][n=68][f=256] (n=64 is k_sum). grid (NCHUNK, 32), 256 thr.
__global__ __launch_bounds__(256, 2) void kv_fused(const bf16_t* __restrict__ Kb,
                                                   const bf16_t* __restrict__ Vb,
                                                   const bf16_t* __restrict__ Wf,
                                                   float* __restrict__ kv_part) {
  __shared__ bf16_t kf_lds[4][64 * 36];  // wave-private kf tile [f_local][s]
  __shared__ bf16_t vt[2][80 * 36];      // dbuf V^T [n][s]; rows 64..79: ones/zeros
  int chunk = blockIdx.x, bh = blockIdx.y;
  int b = bh >> 4, h = bh & 15;
  int lane = threadIdx.x & 63, wid = threadIdx.x >> 6;
  int lr = lane & 15, lg = lane >> 4;
  int f0 = wid * 64;
  // init ones/zero rows of both vt buffers (never rewritten)
  for (int i = threadIdx.x; i < 2 * 16 * 36; i += 256) {
    int bufn = i / (16 * 36), rem = i % (16 * 36);
    int n = rem / 36, s = rem % 36;
    vt[bufn][(64 + n) * 36 + s] = (n == 0) ? (__bf16)1.0f : (__bf16)0.0f;
  }
  bfv8 wf[4][2];
#pragma unroll
  for (int ft = 0; ft < 4; ++ft)
#pragma unroll
    for (int kk = 0; kk < 2; ++kk)
      wf[ft][kk] = *reinterpret_cast<const bfv8*>(Wf + (size_t)(f0 + ft * 16 + lr) * HDIM + kk * 32 + lg * 8);
  int si = threadIdx.x >> 3, c8 = threadIdx.x & 7;
  const bf16_t* Kbase = Kb + (size_t)b * SEQ * DIM + h * HDIM;
  const bf16_t* Vbase = Vb + (size_t)b * SEQ * DIM + h * HDIM;
  int s0 = chunk * (SEQ / NCHUNK);

  // preamble: V(0) -> vt[0]; V(1), K(0) -> regs
  bfv8 vv0 = *reinterpret_cast<const bfv8*>(Vbase + (size_t)(s0 + si) * DIM + c8 * 8);
  bfv8 vvA = *reinterpret_cast<const bfv8*>(Vbase + (size_t)(s0 + 32 + si) * DIM + c8 * 8);
  bfv8 vvB;
  bfv8 krgA[2][2], krgB[2][2];
#pragma unroll
  for (int st = 0; st < 2; ++st)
#pragma unroll
    for (int kk = 0; kk < 2; ++kk)
      krgA[st][kk] = *reinterpret_cast<const bfv8*>(Kbase + (size_t)(s0 + st * 16 + lr) * DIM + kk * 32 + lg * 8);
#pragma unroll
  for (int j = 0; j < 8; ++j) vt[0][(c8 * 8 + j) * 36 + si] = vv0[j];
  asm volatile("s_waitcnt lgkmcnt(0)" ::: "memory");
  __builtin_amdgcn_s_barrier();

  f32x4 acc[4][5] = {};

  auto STEP = [&](int it, bfv8(&krgC)[2][2], bfv8& vvC, bfv8(&krgN)[2][2], bfv8& vvN,
                  int cur) __attribute__((always_inline)) {
    int sbn = s0 + (it + 1) * 32;
    // prefetch K(it+1), V(it+2) — stay in flight across the raw barrier
    if (it + 1 < KV_NIT) {
#pragma unroll
      for (int st = 0; st < 2; ++st)
#pragma unroll
        for (int kk = 0; kk < 2; ++kk)
          krgN[st][kk] = *reinterpret_cast<const bfv8*>(Kbase + (size_t)(sbn + st * 16 + lr) * DIM + kk * 32 + lg * 8);
      if (it + 2 < KV_NIT)
        vvN = *reinterpret_cast<const bfv8*>(Vbase + (size_t)(sbn + 32 + si) * DIM + c8 * 8);
    }
    // kf-gen (wave-local f-range), C[f][s]
    f32x4 ckf[4][2] = {};
#pragma unroll
    for (int ft = 0; ft < 4; ++ft)
#pragma unroll
      for (int st = 0; st < 2; ++st)
#pragma unroll
        for (int kk = 0; kk < 2; ++kk) ckf[ft][st] = mfma_bf16(wf[ft][kk], krgC[st][kk], ckf[ft][st]);
    // write vt[cur^1] with V(it+1), for next iteration (guarded last iter)
    if (it + 1 < KV_NIT) {
#pragma unroll
      for (int j = 0; j < 8; ++j) vt[cur ^ 1][(c8 * 8 + j) * 36 + si] = vvC[j];
    }
    // write own kf tile (elu+1)
#pragma unroll
    for (int ft = 0; ft < 4; ++ft)
#pragma unroll
      for (int st = 0; st < 2; ++st)
#pragma unroll
        for (int q = 0; q < 4; ++q) {
          float x = ckf[ft][st][q];
          x = (x > 0.0f) ? (x + 1.0f) : __expf(x);
          kf_lds[wid][(ft * 16 + lg * 4 + q) * 36 + st * 16 + lr] = (__bf16)x;
        }
    // fragments: af from own kf (in-wave lgkm ordering), bg from vt[cur] (barrier'd last iter)
    bfv8 af[4], bg[5];
#pragma unroll
    for (int ft = 0; ft < 4; ++ft)
      af[ft] = *reinterpret_cast<const bfv8*>(&kf_lds[wid][(ft * 16 + lr) * 36 + lg * 8]);
#pragma unroll
    for (int nt = 0; nt < 5; ++nt)
      bg[nt] = *reinterpret_cast<const bfv8*>(&vt[cur][(nt * 16 + lr) * 36 + lg * 8]);
#pragma unroll
    for (int ft = 0; ft < 4; ++ft)
#pragma unroll
      for (int nt = 0; nt < 5; ++nt) acc[ft][nt] = mfma_bf16(af[ft], bg[nt], acc[ft][nt]);
    asm volatile("s_waitcnt lgkmcnt(0)" ::: "memory");
    __builtin_amdgcn_s_barrier();  // raw: vmem prefetches stay in flight
  };

  for (int it2 = 0; it2 < KV_NIT; it2 += 2) {
    STEP(it2, krgA, vvA, krgB, vvB, 0);
    STEP(it2 + 1, krgB, vvB, krgA, vvA, 1);
  }

  float* outb = kv_part + ((size_t)chunk * 32 + bh) * 68 * FDIM;
#pragma unroll
  for (int ft = 0; ft < 4; ++ft)
#pragma unroll
    for (int nt = 0; nt < 5; ++nt) {
      int n = nt * 16 + lr;
      if (nt < 4 || lr < 4)
        *reinterpret_cast<f32x4*>(&outb[(size_t)n * FDIM + f0 + ft * 16 + lg * 4]) = acc[ft][nt];
    }
}

// ---------------- reduce NCHUNK partials -> kvT bf16 [bh][n=80][f=256] ----------------
__global__ __launch_bounds__(256) void kv_reduce(const float* __restrict__ part,
                                                 bf16_t* __restrict__ kvT) {
  int i = blockIdx.x * 256 + threadIdx.x;  // 32*80*256 = 655360
  int n = (i >> 8) % 80;
  int bh = i / (80 * 256);
  int f = i & 255;
  float s = 0.0f;
  if (n < 68) {
#pragma unroll
    for (int c = 0; c < NCHUNK; ++c)
      s += part[(((size_t)c * 32 + bh) * 68 + n) * FDIM + f];
  }
  kvT[i] = (__bf16)s;
}

// ------- fused featq+readout: outp = (qf @ kv) / (qf . ksum + 1e-6), grid (M/64, NH) ------
__global__ __launch_bounds__(256) void attn_fused(const bf16_t* __restrict__ Qb,
                                                  const bf16_t* __restrict__ Wf,
                                                  const bf16_t* __restrict__ kvT,
                                                  bf16_t* __restrict__ outp) {
  __shared__ bf16_t qf_lds[64 * 264];
  int rb = blockIdx.x, h = blockIdx.y;
  int row0 = rb * 64;
  int bh = (row0 >> 13) * NH + h;  // SEQ = 8192 rows per batch
  int lane = threadIdx.x & 63, wid = threadIdx.x >> 6;
  int lr = lane & 15, lg = lane >> 4;
  int f0 = wid * 64;
  bfv8 qa[4][2], wfb[4][2];
#pragma unroll
  for (int t = 0; t < 4; ++t)
#pragma unroll
    for (int kk = 0; kk < 2; ++kk) {
      qa[t][kk] = *reinterpret_cast<const bfv8*>(Qb + (size_t)(row0 + t * 16 + lr) * DIM + h * HDIM + kk * 32 + lg * 8);
      wfb[t][kk] = *reinterpret_cast<const bfv8*>(Wf + (size_t)(f0 + t * 16 + lr) * HDIM + kk * 32 + lg * 8);
    }
  f32x4 cq[4][4] = {};
#pragma unroll
  for (int rt = 0; rt < 4; ++rt)
#pragma unroll
    for (int ft = 0; ft < 4; ++ft)
#pragma unroll
      for (int kk = 0; kk < 2; ++kk) cq[rt][ft] = mfma_bf16(qa[rt][kk], wfb[ft][kk], cq[rt][ft]);
#pragma unroll
  for (int rt = 0; rt < 4; ++rt)
#pragma unroll
    for (int ft = 0; ft < 4; ++ft)
#pragma unroll
      for (int q = 0; q < 4; ++q) {
        float x = cq[rt][ft][q];
        x = (x > 0.0f) ? (x + 1.0f) : __expf(x);
        qf_lds[(size_t)(rt * 16 + lg * 4 + q) * 264 + f0 + ft * 16 + lr] = (__bf16)x;
      }
  const bf16_t* Bp = kvT + (size_t)bh * 80 * FDIM;
  // prefetch ks=0 B-fragments before the raw barrier (stay in flight)
  bfv8 bgc[5], bgn[5];
#pragma unroll
  for (int nt = 0; nt < 5; ++nt)
    bgc[nt] = *reinterpret_cast<const bfv8*>(Bp + (size_t)(nt * 16 + lr) * FDIM + lg * 8);
  asm volatile("s_waitcnt lgkmcnt(0)" ::: "memory");
  __builtin_amdgcn_s_barrier();
  f32x4 acc[5] = {};
#pragma unroll
  for (int ks = 0; ks < 8; ++ks) {
    if (ks < 7) {
#pragma unroll
      for (int nt = 0; nt < 5; ++nt)
        bgn[nt] = *reinterpret_cast<const bfv8*>(Bp + (size_t)(nt * 16 + lr) * FDIM + (ks + 1) * 32 + lg * 8);
    }
    bfv8 a = *reinterpret_cast<const bfv8*>(&qf_lds[(size_t)(wid * 16 + lr) * 264 + ks * 32 + lg * 8]);
#pragma unroll
    for (int nt = 0; nt < 5; ++nt) acc[nt] = mfma_bf16(a, bgc[nt], acc[nt]);
#pragma unroll
    for (int nt = 0; nt < 5; ++nt) bgc[nt] = bgn[nt];
  }
#pragma unroll
  for (int q = 0; q < 4; ++q) {
    float nrm = __shfl(acc[4][q], (lane & 48)) + 1e-6f;
    int r = row0 + wid * 16 + lg * 4 + q;
#pragma unroll
    for (int nt = 0; nt < 4; ++nt)
      outp[(size_t)r * DIM + h * HDIM + nt * 16 + lr] = (__bf16)(acc[nt][q] / nrm);
  }
}

extern "C" void kernel_launch(void* const* d_in, const int* in_sizes, int n_in,
                              void* d_out, int out_size, void* d_ws, size_t ws_size,
                              hipStream_t stream) {
  const float* X  = (const float*)d_in[0];
  const float* Wq = (const float*)d_in[1];
  const float* Wk = (const float*)d_in[2];
  const float* Wv = (const float*)d_in[3];
  const float* Wo = (const float*)d_in[4];
  const float* Wf = (const float*)d_in[5];
  float* out = (float*)d_out;
  char* ws = (char*)d_ws;
  const size_t MB = 1ull << 20;
  if (ws_size < 75 * MB) return;

  // arena (75 MB) + d_out (64 MB) as scratch for K/V
  bf16_t* Xb  = (bf16_t*)(ws + 0 * MB);    // 32MB; dead after gemm_qkv
  bf16_t* W3  = (bf16_t*)(ws + 32 * MB);   // 6MB;  dead after gemm_qkv
  bf16_t* Qb  = (bf16_t*)(ws + 38 * MB);   // 32MB; live until attn_fused
  bf16_t* Wob = (bf16_t*)(ws + 70 * MB);   // 2MB;  live until gemm_final
  bf16_t* Wfb = (bf16_t*)(ws + 72 * MB);   // 32KB
  bf16_t* kvT = (bf16_t*)(ws + 73 * MB);   // 1.31MB
  float* kv_part = (float*)(ws + 0 * MB);  // 34MB over dead Xb+W3
  bf16_t* outp = (bf16_t*)(ws + 0 * MB);   // 32MB over dead kv_part
  bf16_t* Kb = (bf16_t*)d_out;             // 32MB scratch in d_out
  bf16_t* Vb = Kb + (size_t)MROWS * DIM;   // 32MB scratch in d_out

  cvt_kernel<<<4096, 256, 0, stream>>>(X, Xb, 16777216 / 4);
  cvt_weights<<<4112, 256, 0, stream>>>(Wq, Wk, Wv, Wo, Wf, W3, Wob, Wfb);

  gemm_qkv<<<dim3(128, 8, 3), 256, 0, stream>>>(Xb, W3, Qb, Kb, Vb);
  kv_fused<<<dim3(NCHUNK, 32), 256, 0, stream>>>(Kb, Vb, Wfb, kv_part);
  kv_reduce<<<2560, 256, 0, stream>>>(kv_part, kvT);
  attn_fused<<<dim3(256, NH), 256, 0, stream>>>(Qb, Wfb, kvT, outp);
  gemm_final<<<dim3(128, 8), 256, 0, stream>>>(outp, Wob, out);
}

// Round 7
// 344.801 us; speedup vs baseline: 1.4162x; 1.0377x over previous
//
#include <hip/hip_runtime.h>
#include <stdint.h>

typedef __bf16 bf16_t;
typedef __attribute__((ext_vector_type(8))) __bf16 bfv8;
typedef __attribute__((ext_vector_type(4))) __bf16 bfv4;
typedef __attribute__((ext_vector_type(4))) float f32x4;

constexpr int BATCH = 2, SEQ = 8192, DIM = 1024, NH = 16, HDIM = 64, FDIM = 256;
constexpr int MROWS = BATCH * SEQ;  // 16384
constexpr int NCHUNK = 16;          // kv s-chunks (512 s each)
constexpr int KV_NIT = (SEQ / NCHUNK) / 32;  // 16 iterations of 32 s
constexpr int KVP_CH = 32 * 256 * 68;        // 557056 floats per chunk ([bh][f][n])

__device__ __forceinline__ f32x4 mfma_bf16(bfv8 a, bfv8 b, f32x4 c) {
  return __builtin_amdgcn_mfma_f32_16x16x32_bf16(a, b, c, 0, 0, 0);
}

// ---- async global->LDS 16B (LDS dst wave-uniform base + lane*16) ----
__device__ __forceinline__ void gload_lds16(const bf16_t* g, bf16_t* lds) {
  auto const* gp = reinterpret_cast<const __attribute__((address_space(1))) uint32_t*>(
      reinterpret_cast<uintptr_t>(g));
  auto* lp = reinterpret_cast<__attribute__((address_space(3))) uint32_t*>(
      reinterpret_cast<uintptr_t>(lds));
  __builtin_amdgcn_global_load_lds(gp, lp, 16, 0, 0);
}

// ---- stage a 128x64 bf16 tile into LDS (linear [128][64]), xor-swizzled source ----
__device__ __forceinline__ void stage128x64(const bf16_t* g_base, int k0,
                                            bf16_t* lds, int wid, int lane) {
#pragma unroll
  for (int j = 0; j < 4; ++j) {
    int r0 = (wid * 4 + j) * 8;                 // wave-uniform
    int g_row = r0 + (lane >> 3);
    int g_slot = (lane & 7) ^ (g_row & 7);
    const bf16_t* src = g_base + (size_t)g_row * DIM + k0 + g_slot * 8;
    gload_lds16(src, lds + r0 * 64);
  }
}

// ---------------- fused fp32 -> bf16 converts: X, Wq,Wk,Wv, Wo, Wf ----------------
// float4 totals: X 4194304; weights 1052672. grid 20496 x 256 (exact).
__global__ __launch_bounds__(256) void cvt_all(const float* __restrict__ X,
                                               const float* __restrict__ Wq,
                                               const float* __restrict__ Wk,
                                               const float* __restrict__ Wv,
                                               const float* __restrict__ Wo,
                                               const float* __restrict__ Wf,
                                               bf16_t* __restrict__ Xb,
                                               bf16_t* __restrict__ W3,
                                               bf16_t* __restrict__ Wob,
                                               bf16_t* __restrict__ Wfb) {
  int i = blockIdx.x * 256 + threadIdx.x;
  const float* src;
  bf16_t* dst;
  int off;
  if (i < 4194304) {
    src = X; dst = Xb; off = i;
  } else {
    int j = i - 4194304;
    if (j < 786432) {
      int seg = j >> 18;
      off = j & 262143;
      src = (seg == 0) ? Wq : ((seg == 1) ? Wk : Wv);
      dst = W3 + (size_t)seg * 1048576;
    } else if (j < 1048576) {
      off = j - 786432; src = Wo; dst = Wob;
    } else {
      off = j - 1048576; src = Wf; dst = Wfb;
    }
  }
  float4 v = reinterpret_cast<const float4*>(src)[off];
  bfv4 o = {(__bf16)v.x, (__bf16)v.y, (__bf16)v.z, (__bf16)v.w};
  reinterpret_cast<bfv4*>(dst)[off] = o;
}

// ---------------- Q/K/V projection: C = X @ W^T (bf16 out), LDS-staged ----------------
__global__ __launch_bounds__(256) void gemm_qkv(const bf16_t* __restrict__ A,
                                                const bf16_t* __restrict__ Wall,
                                                bf16_t* __restrict__ Q,
                                                bf16_t* __restrict__ K,
                                                bf16_t* __restrict__ V) {
  __shared__ bf16_t As[128 * 64];
  __shared__ bf16_t Bs[128 * 64];
  int z = blockIdx.z;
  const bf16_t* Wm = Wall + (size_t)z * (DIM * DIM);
  bf16_t* C = (z == 0) ? Q : ((z == 1) ? K : V);
  int lane = threadIdx.x & 63, wid = threadIdx.x >> 6;
  int lr = lane & 15, lg = lane >> 4;
  int wr = wid >> 1, wc = wid & 1;
  int brow = blockIdx.x * 128, bcol = blockIdx.y * 128;
  const bf16_t* Ab = A + (size_t)brow * DIM;
  const bf16_t* Bb = Wm + (size_t)bcol * DIM;
  f32x4 acc[4][4] = {};
  for (int ks = 0; ks < DIM / 64; ++ks) {
    stage128x64(Ab, ks * 64, As, wid, lane);
    stage128x64(Bb, ks * 64, Bs, wid, lane);
    __syncthreads();
#pragma unroll
    for (int kk = 0; kk < 2; ++kk) {
      bfv8 af[4], bg[4];
#pragma unroll
      for (int t = 0; t < 4; ++t) {
        int ar = wr * 64 + t * 16 + lr;
        af[t] = *reinterpret_cast<const bfv8*>(&As[ar * 64 + (((kk * 4 + lg) ^ (ar & 7)) * 8)]);
        int br = wc * 64 + t * 16 + lr;
        bg[t] = *reinterpret_cast<const bfv8*>(&Bs[br * 64 + (((kk * 4 + lg) ^ (br & 7)) * 8)]);
      }
#pragma unroll
      for (int i = 0; i < 4; ++i)
#pragma unroll
        for (int j = 0; j < 4; ++j) acc[i][j] = mfma_bf16(af[i], bg[j], acc[i][j]);
    }
    __syncthreads();
  }
#pragma unroll
  for (int i = 0; i < 4; ++i) {
    int r = brow + wr * 64 + i * 16 + lg * 4;
#pragma unroll
    for (int j = 0; j < 4; ++j) {
      int c = bcol + wc * 64 + j * 16 + lr;
#pragma unroll
      for (int q = 0; q < 4; ++q) C[(size_t)(r + q) * DIM + c] = (__bf16)acc[i][j][q];
    }
  }
}

// ---------------- final: d_out = out_pre @ Wo^T (fp32 out), LDS-staged ----------------
__global__ __launch_bounds__(256) void gemm_final(const bf16_t* __restrict__ A,
                                                  const bf16_t* __restrict__ W,
                                                  float* __restrict__ C) {
  __shared__ bf16_t As[128 * 64];
  __shared__ bf16_t Bs[128 * 64];
  int lane = threadIdx.x & 63, wid = threadIdx.x >> 6;
  int lr = lane & 15, lg = lane >> 4;
  int wr = wid >> 1, wc = wid & 1;
  int brow = blockIdx.x * 128, bcol = blockIdx.y * 128;
  const bf16_t* Ab = A + (size_t)brow * DIM;
  const bf16_t* Bb = W + (size_t)bcol * DIM;
  f32x4 acc[4][4] = {};
  for (int ks = 0; ks < DIM / 64; ++ks) {
    stage128x64(Ab, ks * 64, As, wid, lane);
    stage128x64(Bb, ks * 64, Bs, wid, lane);
    __syncthreads();
#pragma unroll
    for (int kk = 0; kk < 2; ++kk) {
      bfv8 af[4], bg[4];
#pragma unroll
      for (int t = 0; t < 4; ++t) {
        int ar = wr * 64 + t * 16 + lr;
        af[t] = *reinterpret_cast<const bfv8*>(&As[ar * 64 + (((kk * 4 + lg) ^ (ar & 7)) * 8)]);
        int br = wc * 64 + t * 16 + lr;
        bg[t] = *reinterpret_cast<const bfv8*>(&Bs[br * 64 + (((kk * 4 + lg) ^ (br & 7)) * 8)]);
      }
#pragma unroll
      for (int i = 0; i < 4; ++i)
#pragma unroll
        for (int j = 0; j < 4; ++j) acc[i][j] = mfma_bf16(af[i], bg[j], acc[i][j]);
    }
    __syncthreads();
  }
#pragma unroll
  for (int i = 0; i < 4; ++i) {
    int r = brow + wr * 64 + i * 16 + lg * 4;
#pragma unroll
    for (int j = 0; j < 4; ++j) {
      int c = bcol + wc * 64 + j * 16 + lr;
#pragma unroll
      for (int q = 0; q < 4; ++q) C[(size_t)(r + q) * DIM + c] = acc[i][j][q];
    }
  }
}

// ------- fused featk+kv v2: 1 raw barrier/iter, wave-private kf, dbuf vt, reg prefetch ----
// kv_part[chunk][bh][f=256][n=68] (n=64 is k_sum; coalesced 64B stores). grid (NCHUNK, 32).
__global__ __launch_bounds__(256, 2) void kv_fused(const bf16_t* __restrict__ Kb,
                                                   const bf16_t* __restrict__ Vb,
                                                   const bf16_t* __restrict__ Wf,
                                                   float* __restrict__ kv_part) {
  __shared__ bf16_t kf_lds[4][64 * 36];  // wave-private kf tile [f_local][s]
  __shared__ bf16_t vt[2][80 * 36];      // dbuf V^T [n][s]; rows 64..79: ones/zeros
  int chunk = blockIdx.x, bh = blockIdx.y;
  int b = bh >> 4, h = bh & 15;
  int lane = threadIdx.x & 63, wid = threadIdx.x >> 6;
  int lr = lane & 15, lg = lane >> 4;
  int f0 = wid * 64;
  for (int i = threadIdx.x; i < 2 * 16 * 36; i += 256) {
    int bufn = i / (16 * 36), rem = i % (16 * 36);
    int n = rem / 36, s = rem % 36;
    vt[bufn][(64 + n) * 36 + s] = (n == 0) ? (__bf16)1.0f : (__bf16)0.0f;
  }
  bfv8 wf[4][2];
#pragma unroll
  for (int ft = 0; ft < 4; ++ft)
#pragma unroll
    for (int kk = 0; kk < 2; ++kk)
      wf[ft][kk] = *reinterpret_cast<const bfv8*>(Wf + (size_t)(f0 + ft * 16 + lr) * HDIM + kk * 32 + lg * 8);
  int si = threadIdx.x >> 3, c8 = threadIdx.x & 7;
  const bf16_t* Kbase = Kb + (size_t)b * SEQ * DIM + h * HDIM;
  const bf16_t* Vbase = Vb + (size_t)b * SEQ * DIM + h * HDIM;
  int s0 = chunk * (SEQ / NCHUNK);

  bfv8 vv0 = *reinterpret_cast<const bfv8*>(Vbase + (size_t)(s0 + si) * DIM + c8 * 8);
  bfv8 vvA = *reinterpret_cast<const bfv8*>(Vbase + (size_t)(s0 + 32 + si) * DIM + c8 * 8);
  bfv8 vvB;
  bfv8 krgA[2][2], krgB[2][2];
#pragma unroll
  for (int st = 0; st < 2; ++st)
#pragma unroll
    for (int kk = 0; kk < 2; ++kk)
      krgA[st][kk] = *reinterpret_cast<const bfv8*>(Kbase + (size_t)(s0 + st * 16 + lr) * DIM + kk * 32 + lg * 8);
#pragma unroll
  for (int j = 0; j < 8; ++j) vt[0][(c8 * 8 + j) * 36 + si] = vv0[j];
  asm volatile("s_waitcnt lgkmcnt(0)" ::: "memory");
  __builtin_amdgcn_s_barrier();

  f32x4 acc[4][5] = {};

  auto STEP = [&](int it, bfv8(&krgC)[2][2], bfv8& vvC, bfv8(&krgN)[2][2], bfv8& vvN,
                  int cur) __attribute__((always_inline)) {
    int sbn = s0 + (it + 1) * 32;
    if (it + 1 < KV_NIT) {
#pragma unroll
      for (int st = 0; st < 2; ++st)
#pragma unroll
        for (int kk = 0; kk < 2; ++kk)
          krgN[st][kk] = *reinterpret_cast<const bfv8*>(Kbase + (size_t)(sbn + st * 16 + lr) * DIM + kk * 32 + lg * 8);
      if (it + 2 < KV_NIT)
        vvN = *reinterpret_cast<const bfv8*>(Vbase + (size_t)(sbn + 32 + si) * DIM + c8 * 8);
    }
    f32x4 ckf[4][2] = {};
#pragma unroll
    for (int ft = 0; ft < 4; ++ft)
#pragma unroll
      for (int st = 0; st < 2; ++st)
#pragma unroll
        for (int kk = 0; kk < 2; ++kk) ckf[ft][st] = mfma_bf16(wf[ft][kk], krgC[st][kk], ckf[ft][st]);
    if (it + 1 < KV_NIT) {
#pragma unroll
      for (int j = 0; j < 8; ++j) vt[cur ^ 1][(c8 * 8 + j) * 36 + si] = vvC[j];
    }
#pragma unroll
    for (int ft = 0; ft < 4; ++ft)
#pragma unroll
      for (int st = 0; st < 2; ++st)
#pragma unroll
        for (int q = 0; q < 4; ++q) {
          float x = ckf[ft][st][q];
          x = (x > 0.0f) ? (x + 1.0f) : __expf(x);
          kf_lds[wid][(ft * 16 + lg * 4 + q) * 36 + st * 16 + lr] = (__bf16)x;
        }
    bfv8 af[4], bg[5];
#pragma unroll
    for (int ft = 0; ft < 4; ++ft)
      af[ft] = *reinterpret_cast<const bfv8*>(&kf_lds[wid][(ft * 16 + lr) * 36 + lg * 8]);
#pragma unroll
    for (int nt = 0; nt < 5; ++nt)
      bg[nt] = *reinterpret_cast<const bfv8*>(&vt[cur][(nt * 16 + lr) * 36 + lg * 8]);
#pragma unroll
    for (int ft = 0; ft < 4; ++ft)
#pragma unroll
      for (int nt = 0; nt < 5; ++nt) acc[ft][nt] = mfma_bf16(af[ft], bg[nt], acc[ft][nt]);
    asm volatile("s_waitcnt lgkmcnt(0)" ::: "memory");
    __builtin_amdgcn_s_barrier();  // raw: vmem prefetches stay in flight
  };

  for (int it2 = 0; it2 < KV_NIT; it2 += 2) {
    STEP(it2, krgA, vvA, krgB, vvB, 0);
    STEP(it2 + 1, krgB, vvB, krgA, vvA, 1);
  }

  // coalesced [f][n] stores: per instr, 16 lanes (lr) x 4B = 64B contiguous
  float* outb = kv_part + ((size_t)chunk * 32 + bh) * (FDIM * 68);
#pragma unroll
  for (int ft = 0; ft < 4; ++ft)
#pragma unroll
    for (int q = 0; q < 4; ++q) {
      int f = f0 + ft * 16 + lg * 4 + q;
#pragma unroll
      for (int nt = 0; nt < 4; ++nt)
        outb[(size_t)f * 68 + nt * 16 + lr] = acc[ft][nt][q];
      if (lr < 4) outb[(size_t)f * 68 + 64 + lr] = acc[ft][4][q];
    }
}

// ------- reduce NCHUNK partials [bh][f][n] -> kvT bf16 [bh][n=80][f] (rows 68..79 = 0) ----
__global__ __launch_bounds__(256) void kv_reduce(const float* __restrict__ part,
                                                 bf16_t* __restrict__ kvT) {
  int i = blockIdx.x * 256 + threadIdx.x;  // grid 2560: 557056 reduce + 98304 zero-fill
  if (i < KVP_CH) {
    int n = i % 68;
    int t = i / 68;  // bh*256 + f
    int f = t & 255, bh = t >> 8;
    float s = 0.0f;
#pragma unroll
    for (int c = 0; c < NCHUNK; ++c) s += part[(size_t)c * KVP_CH + i];
    kvT[((size_t)bh * 80 + n) * FDIM + f] = (__bf16)s;
  } else {
    int j = i - KVP_CH;  // 32*12*256
    int f = j & 255;
    int t = j >> 8;  // bh*12 + (n-68)
    int n = 68 + t % 12, bh = t / 12;
    kvT[((size_t)bh * 80 + n) * FDIM + f] = (__bf16)0.0f;
  }
}

// ------- fused featq+readout: outp = (qf @ kv) / (qf . ksum + 1e-6), grid (M/64, NH) ------
__global__ __launch_bounds__(256) void attn_fused(const bf16_t* __restrict__ Qb,
                                                  const bf16_t* __restrict__ Wf,
                                                  const bf16_t* __restrict__ kvT,
                                                  bf16_t* __restrict__ outp) {
  __shared__ bf16_t qf_lds[64 * 264];
  int rb = blockIdx.x, h = blockIdx.y;
  int row0 = rb * 64;
  int bh = (row0 >> 13) * NH + h;  // SEQ = 8192 rows per batch
  int lane = threadIdx.x & 63, wid = threadIdx.x >> 6;
  int lr = lane & 15, lg = lane >> 4;
  int f0 = wid * 64;
  bfv8 qa[4][2], wfb[4][2];
#pragma unroll
  for (int t = 0; t < 4; ++t)
#pragma unroll
    for (int kk = 0; kk < 2; ++kk) {
      qa[t][kk] = *reinterpret_cast<const bfv8*>(Qb + (size_t)(row0 + t * 16 + lr) * DIM + h * HDIM + kk * 32 + lg * 8);
      wfb[t][kk] = *reinterpret_cast<const bfv8*>(Wf + (size_t)(f0 + t * 16 + lr) * HDIM + kk * 32 + lg * 8);
    }
  f32x4 cq[4][4] = {};
#pragma unroll
  for (int rt = 0; rt < 4; ++rt)
#pragma unroll
    for (int ft = 0; ft < 4; ++ft)
#pragma unroll
      for (int kk = 0; kk < 2; ++kk) cq[rt][ft] = mfma_bf16(qa[rt][kk], wfb[ft][kk], cq[rt][ft]);
#pragma unroll
  for (int rt = 0; rt < 4; ++rt)
#pragma unroll
    for (int ft = 0; ft < 4; ++ft)
#pragma unroll
      for (int q = 0; q < 4; ++q) {
        float x = cq[rt][ft][q];
        x = (x > 0.0f) ? (x + 1.0f) : __expf(x);
        qf_lds[(size_t)(rt * 16 + lg * 4 + q) * 264 + f0 + ft * 16 + lr] = (__bf16)x;
      }
  const bf16_t* Bp = kvT + (size_t)bh * 80 * FDIM;
  bfv8 bgc[5], bgn[5];
#pragma unroll
  for (int nt = 0; nt < 5; ++nt)
    bgc[nt] = *reinterpret_cast<const bfv8*>(Bp + (size_t)(nt * 16 + lr) * FDIM + lg * 8);
  asm volatile("s_waitcnt lgkmcnt(0)" ::: "memory");
  __builtin_amdgcn_s_barrier();
  f32x4 acc[5] = {};
#pragma unroll
  for (int ks = 0; ks < 8; ++ks) {
    if (ks < 7) {
#pragma unroll
      for (int nt = 0; nt < 5; ++nt)
        bgn[nt] = *reinterpret_cast<const bfv8*>(Bp + (size_t)(nt * 16 + lr) * FDIM + (ks + 1) * 32 + lg * 8);
    }
    bfv8 a = *reinterpret_cast<const bfv8*>(&qf_lds[(size_t)(wid * 16 + lr) * 264 + ks * 32 + lg * 8]);
#pragma unroll
    for (int nt = 0; nt < 5; ++nt) acc[nt] = mfma_bf16(a, bgc[nt], acc[nt]);
#pragma unroll
    for (int nt = 0; nt < 5; ++nt) bgc[nt] = bgn[nt];
  }
  // normalize -> stage out tile in LDS (reuse qf_lds) -> coalesced 128B-row stores
  __syncthreads();  // all waves done reading qf_lds
#pragma unroll
  for (int q = 0; q < 4; ++q) {
    float nrm = __shfl(acc[4][q], (lane & 48)) + 1e-6f;
    int row = wid * 16 + lg * 4 + q;
#pragma unroll
    for (int nt = 0; nt < 4; ++nt)
      qf_lds[(size_t)row * 264 + nt * 16 + lr] = (__bf16)(acc[nt][q] / nrm);
  }
  __syncthreads();
#pragma unroll
  for (int rep = 0; rep < 2; ++rep) {
    int id = rep * 256 + threadIdx.x;
    int row = id >> 3, c8 = id & 7;
    bfv8 v = *reinterpret_cast<const bfv8*>(&qf_lds[(size_t)row * 264 + c8 * 8]);
    *reinterpret_cast<bfv8*>(&outp[(size_t)(row0 + row) * DIM + h * HDIM + c8 * 8]) = v;
  }
}

extern "C" void kernel_launch(void* const* d_in, const int* in_sizes, int n_in,
                              void* d_out, int out_size, void* d_ws, size_t ws_size,
                              hipStream_t stream) {
  const float* X  = (const float*)d_in[0];
  const float* Wq = (const float*)d_in[1];
  const float* Wk = (const float*)d_in[2];
  const float* Wv = (const float*)d_in[3];
  const float* Wo = (const float*)d_in[4];
  const float* Wf = (const float*)d_in[5];
  float* out = (float*)d_out;
  char* ws = (char*)d_ws;
  const size_t MB = 1ull << 20;
  if (ws_size < 75 * MB) return;

  // arena (75 MB) + d_out (64 MB) as scratch for K/V
  bf16_t* Xb  = (bf16_t*)(ws + 0 * MB);    // 32MB; dead after gemm_qkv
  bf16_t* W3  = (bf16_t*)(ws + 32 * MB);   // 6MB;  dead after gemm_qkv
  bf16_t* Qb  = (bf16_t*)(ws + 38 * MB);   // 32MB; live until attn_fused
  bf16_t* Wob = (bf16_t*)(ws + 70 * MB);   // 2MB;  live until gemm_final
  bf16_t* Wfb = (bf16_t*)(ws + 72 * MB);   // 32KB
  bf16_t* kvT = (bf16_t*)(ws + 73 * MB);   // 1.31MB
  float* kv_part = (float*)(ws + 0 * MB);  // 35.7MB over dead Xb+W3
  bf16_t* outp = (bf16_t*)(ws + 0 * MB);   // 32MB over dead kv_part
  bf16_t* Kb = (bf16_t*)d_out;             // 32MB scratch in d_out
  bf16_t* Vb = Kb + (size_t)MROWS * DIM;   // 32MB scratch in d_out

  cvt_all<<<20496, 256, 0, stream>>>(X, Wq, Wk, Wv, Wo, Wf, Xb, W3, Wob, Wfb);

  gemm_qkv<<<dim3(128, 8, 3), 256, 0, stream>>>(Xb, W3, Qb, Kb, Vb);
  kv_fused<<<dim3(NCHUNK, 32), 256, 0, stream>>>(Kb, Vb, Wfb, kv_part);
  kv_reduce<<<2560, 256, 0, stream>>>(kv_part, kvT);
  attn_fused<<<dim3(256, NH), 256, 0, stream>>>(Qb, Wfb, kvT, outp);
  gemm_final<<<dim3(128, 8), 256, 0, stream>>>(outp, Wob, out);
}

// Round 8
// 301.002 us; speedup vs baseline: 1.6222x; 1.1455x over previous
//
#include <hip/hip_runtime.h>
#include <stdint.h>

typedef __bf16 bf16_t;
typedef __attribute__((ext_vector_type(8))) __bf16 bfv8;
typedef __attribute__((ext_vector_type(4))) __bf16 bfv4;
typedef __attribute__((ext_vector_type(4))) float f32x4;

constexpr int BATCH = 2, SEQ = 8192, DIM = 1024, NH = 16, HDIM = 64, FDIM = 256;
constexpr int MROWS = BATCH * SEQ;  // 16384
constexpr int NCHUNK = 16;          // kv s-chunks (512 s each)
constexpr int KV_NIT = (SEQ / NCHUNK) / 32;  // 16 iterations of 32 s
constexpr int KVP_CH = 32 * 256 * 68;        // 557056 floats per chunk ([bh][f][n])

__device__ __forceinline__ f32x4 mfma_bf16(bfv8 a, bfv8 b, f32x4 c) {
  return __builtin_amdgcn_mfma_f32_16x16x32_bf16(a, b, c, 0, 0, 0);
}

// ---- async global->LDS 16B (LDS dst wave-uniform base + lane*16) ----
__device__ __forceinline__ void gload_lds16(const bf16_t* g, bf16_t* lds) {
  auto const* gp = reinterpret_cast<const __attribute__((address_space(1))) uint32_t*>(
      reinterpret_cast<uintptr_t>(g));
  auto* lp = reinterpret_cast<__attribute__((address_space(3))) uint32_t*>(
      reinterpret_cast<uintptr_t>(lds));
  __builtin_amdgcn_global_load_lds(gp, lp, 16, 0, 0);
}

// ---- stage a 128x64 bf16 tile into LDS (linear [128][64]), xor-swizzled source ----
__device__ __forceinline__ void stage128x64(const bf16_t* g_base, int k0,
                                            bf16_t* lds, int wid, int lane) {
#pragma unroll
  for (int j = 0; j < 4; ++j) {
    int r0 = (wid * 4 + j) * 8;                 // wave-uniform
    int g_row = r0 + (lane >> 3);
    int g_slot = (lane & 7) ^ (g_row & 7);
    const bf16_t* src = g_base + (size_t)g_row * DIM + k0 + g_slot * 8;
    gload_lds16(src, lds + r0 * 64);
  }
}

// ---------------- fused fp32 -> bf16 converts: X, Wq,Wk,Wv, Wo, Wf ----------------
__global__ __launch_bounds__(256) void cvt_all(const float* __restrict__ X,
                                               const float* __restrict__ Wq,
                                               const float* __restrict__ Wk,
                                               const float* __restrict__ Wv,
                                               const float* __restrict__ Wo,
                                               const float* __restrict__ Wf,
                                               bf16_t* __restrict__ Xb,
                                               bf16_t* __restrict__ W3,
                                               bf16_t* __restrict__ Wob,
                                               bf16_t* __restrict__ Wfb) {
  int i = blockIdx.x * 256 + threadIdx.x;
  const float* src;
  bf16_t* dst;
  int off;
  if (i < 4194304) {
    src = X; dst = Xb; off = i;
  } else {
    int j = i - 4194304;
    if (j < 786432) {
      int seg = j >> 18;
      off = j & 262143;
      src = (seg == 0) ? Wq : ((seg == 1) ? Wk : Wv);
      dst = W3 + (size_t)seg * 1048576;
    } else if (j < 1048576) {
      off = j - 786432; src = Wo; dst = Wob;
    } else {
      off = j - 1048576; src = Wf; dst = Wfb;
    }
  }
  float4 v = reinterpret_cast<const float4*>(src)[off];
  bfv4 o = {(__bf16)v.x, (__bf16)v.y, (__bf16)v.z, (__bf16)v.w};
  reinterpret_cast<bfv4*>(dst)[off] = o;
}

// ---------------- Q/K/V projection: C = X @ W^T (bf16 out), LDS-staged ----------------
__global__ __launch_bounds__(256) void gemm_qkv(const bf16_t* __restrict__ A,
                                                const bf16_t* __restrict__ Wall,
                                                bf16_t* __restrict__ Q,
                                                bf16_t* __restrict__ K,
                                                bf16_t* __restrict__ V) {
  __shared__ bf16_t As[128 * 64];
  __shared__ bf16_t Bs[128 * 64];
  int z = blockIdx.z;
  const bf16_t* Wm = Wall + (size_t)z * (DIM * DIM);
  bf16_t* C = (z == 0) ? Q : ((z == 1) ? K : V);
  int lane = threadIdx.x & 63, wid = threadIdx.x >> 6;
  int lr = lane & 15, lg = lane >> 4;
  int wr = wid >> 1, wc = wid & 1;
  int brow = blockIdx.x * 128, bcol = blockIdx.y * 128;
  const bf16_t* Ab = A + (size_t)brow * DIM;
  const bf16_t* Bb = Wm + (size_t)bcol * DIM;
  f32x4 acc[4][4] = {};
  for (int ks = 0; ks < DIM / 64; ++ks) {
    stage128x64(Ab, ks * 64, As, wid, lane);
    stage128x64(Bb, ks * 64, Bs, wid, lane);
    __syncthreads();
#pragma unroll
    for (int kk = 0; kk < 2; ++kk) {
      bfv8 af[4], bg[4];
#pragma unroll
      for (int t = 0; t < 4; ++t) {
        int ar = wr * 64 + t * 16 + lr;
        af[t] = *reinterpret_cast<const bfv8*>(&As[ar * 64 + (((kk * 4 + lg) ^ (ar & 7)) * 8)]);
        int br = wc * 64 + t * 16 + lr;
        bg[t] = *reinterpret_cast<const bfv8*>(&Bs[br * 64 + (((kk * 4 + lg) ^ (br & 7)) * 8)]);
      }
#pragma unroll
      for (int i = 0; i < 4; ++i)
#pragma unroll
        for (int j = 0; j < 4; ++j) acc[i][j] = mfma_bf16(af[i], bg[j], acc[i][j]);
    }
    __syncthreads();
  }
#pragma unroll
  for (int i = 0; i < 4; ++i) {
    int r = brow + wr * 64 + i * 16 + lg * 4;
#pragma unroll
    for (int j = 0; j < 4; ++j) {
      int c = bcol + wc * 64 + j * 16 + lr;
#pragma unroll
      for (int q = 0; q < 4; ++q) C[(size_t)(r + q) * DIM + c] = (__bf16)acc[i][j][q];
    }
  }
}

// ---------------- final: d_out = out_pre @ Wo^T (fp32 out), LDS-staged ----------------
__global__ __launch_bounds__(256) void gemm_final(const bf16_t* __restrict__ A,
                                                  const bf16_t* __restrict__ W,
                                                  float* __restrict__ C) {
  __shared__ bf16_t As[128 * 64];
  __shared__ bf16_t Bs[128 * 64];
  int lane = threadIdx.x & 63, wid = threadIdx.x >> 6;
  int lr = lane & 15, lg = lane >> 4;
  int wr = wid >> 1, wc = wid & 1;
  int brow = blockIdx.x * 128, bcol = blockIdx.y * 128;
  const bf16_t* Ab = A + (size_t)brow * DIM;
  const bf16_t* Bb = W + (size_t)bcol * DIM;
  f32x4 acc[4][4] = {};
  for (int ks = 0; ks < DIM / 64; ++ks) {
    stage128x64(Ab, ks * 64, As, wid, lane);
    stage128x64(Bb, ks * 64, Bs, wid, lane);
    __syncthreads();
#pragma unroll
    for (int kk = 0; kk < 2; ++kk) {
      bfv8 af[4], bg[4];
#pragma unroll
      for (int t = 0; t < 4; ++t) {
        int ar = wr * 64 + t * 16 + lr;
        af[t] = *reinterpret_cast<const bfv8*>(&As[ar * 64 + (((kk * 4 + lg) ^ (ar & 7)) * 8)]);
        int br = wc * 64 + t * 16 + lr;
        bg[t] = *reinterpret_cast<const bfv8*>(&Bs[br * 64 + (((kk * 4 + lg) ^ (br & 7)) * 8)]);
      }
#pragma unroll
      for (int i = 0; i < 4; ++i)
#pragma unroll
        for (int j = 0; j < 4; ++j) acc[i][j] = mfma_bf16(af[i], bg[j], acc[i][j]);
    }
    __syncthreads();
  }
#pragma unroll
  for (int i = 0; i < 4; ++i) {
    int r = brow + wr * 64 + i * 16 + lg * 4;
#pragma unroll
    for (int j = 0; j < 4; ++j) {
      int c = bcol + wc * 64 + j * 16 + lr;
#pragma unroll
      for (int q = 0; q < 4; ++q) C[(size_t)(r + q) * DIM + c] = acc[i][j][q];
    }
  }
}

// ------- fused featk+kv v2: 1 raw barrier/iter, wave-private kf, dbuf vt, reg prefetch ----
// kv_part[chunk][bh][f=256][n=68] (n=64 is k_sum; coalesced 64B stores). grid (NCHUNK, 32).
__global__ __launch_bounds__(256, 2) void kv_fused(const bf16_t* __restrict__ Kb,
                                                   const bf16_t* __restrict__ Vb,
                                                   const bf16_t* __restrict__ Wf,
                                                   float* __restrict__ kv_part) {
  __shared__ bf16_t kf_lds[4][64 * 36];  // wave-private kf tile [f_local][s]
  __shared__ bf16_t vt[2][80 * 36];      // dbuf V^T [n][s]; rows 64..79: ones/zeros
  int chunk = blockIdx.x, bh = blockIdx.y;
  int b = bh >> 4, h = bh & 15;
  int lane = threadIdx.x & 63, wid = threadIdx.x >> 6;
  int lr = lane & 15, lg = lane >> 4;
  int f0 = wid * 64;
  for (int i = threadIdx.x; i < 2 * 16 * 36; i += 256) {
    int bufn = i / (16 * 36), rem = i % (16 * 36);
    int n = rem / 36, s = rem % 36;
    vt[bufn][(64 + n) * 36 + s] = (n == 0) ? (__bf16)1.0f : (__bf16)0.0f;
  }
  bfv8 wf[4][2];
#pragma unroll
  for (int ft = 0; ft < 4; ++ft)
#pragma unroll
    for (int kk = 0; kk < 2; ++kk)
      wf[ft][kk] = *reinterpret_cast<const bfv8*>(Wf + (size_t)(f0 + ft * 16 + lr) * HDIM + kk * 32 + lg * 8);
  int si = threadIdx.x >> 3, c8 = threadIdx.x & 7;
  const bf16_t* Kbase = Kb + (size_t)b * SEQ * DIM + h * HDIM;
  const bf16_t* Vbase = Vb + (size_t)b * SEQ * DIM + h * HDIM;
  int s0 = chunk * (SEQ / NCHUNK);

  bfv8 vv0 = *reinterpret_cast<const bfv8*>(Vbase + (size_t)(s0 + si) * DIM + c8 * 8);
  bfv8 vvA = *reinterpret_cast<const bfv8*>(Vbase + (size_t)(s0 + 32 + si) * DIM + c8 * 8);
  bfv8 vvB;
  bfv8 krgA[2][2], krgB[2][2];
#pragma unroll
  for (int st = 0; st < 2; ++st)
#pragma unroll
    for (int kk = 0; kk < 2; ++kk)
      krgA[st][kk] = *reinterpret_cast<const bfv8*>(Kbase + (size_t)(s0 + st * 16 + lr) * DIM + kk * 32 + lg * 8);
#pragma unroll
  for (int j = 0; j < 8; ++j) vt[0][(c8 * 8 + j) * 36 + si] = vv0[j];
  asm volatile("s_waitcnt lgkmcnt(0)" ::: "memory");
  __builtin_amdgcn_s_barrier();

  f32x4 acc[4][5] = {};

  auto STEP = [&](int it, bfv8(&krgC)[2][2], bfv8& vvC, bfv8(&krgN)[2][2], bfv8& vvN,
                  int cur) __attribute__((always_inline)) {
    int sbn = s0 + (it + 1) * 32;
    if (it + 1 < KV_NIT) {
#pragma unroll
      for (int st = 0; st < 2; ++st)
#pragma unroll
        for (int kk = 0; kk < 2; ++kk)
          krgN[st][kk] = *reinterpret_cast<const bfv8*>(Kbase + (size_t)(sbn + st * 16 + lr) * DIM + kk * 32 + lg * 8);
      if (it + 2 < KV_NIT)
        vvN = *reinterpret_cast<const bfv8*>(Vbase + (size_t)(sbn + 32 + si) * DIM + c8 * 8);
    }
    f32x4 ckf[4][2] = {};
#pragma unroll
    for (int ft = 0; ft < 4; ++ft)
#pragma unroll
      for (int st = 0; st < 2; ++st)
#pragma unroll
        for (int kk = 0; kk < 2; ++kk) ckf[ft][st] = mfma_bf16(wf[ft][kk], krgC[st][kk], ckf[ft][st]);
    if (it + 1 < KV_NIT) {
#pragma unroll
      for (int j = 0; j < 8; ++j) vt[cur ^ 1][(c8 * 8 + j) * 36 + si] = vvC[j];
    }
#pragma unroll
    for (int ft = 0; ft < 4; ++ft)
#pragma unroll
      for (int st = 0; st < 2; ++st)
#pragma unroll
        for (int q = 0; q < 4; ++q) {
          float x = ckf[ft][st][q];
          x = (x > 0.0f) ? (x + 1.0f) : __expf(x);
          kf_lds[wid][(ft * 16 + lg * 4 + q) * 36 + st * 16 + lr] = (__bf16)x;
        }
    bfv8 af[4], bg[5];
#pragma unroll
    for (int ft = 0; ft < 4; ++ft)
      af[ft] = *reinterpret_cast<const bfv8*>(&kf_lds[wid][(ft * 16 + lr) * 36 + lg * 8]);
#pragma unroll
    for (int nt = 0; nt < 5; ++nt)
      bg[nt] = *reinterpret_cast<const bfv8*>(&vt[cur][(nt * 16 + lr) * 36 + lg * 8]);
#pragma unroll
    for (int ft = 0; ft < 4; ++ft)
#pragma unroll
      for (int nt = 0; nt < 5; ++nt) acc[ft][nt] = mfma_bf16(af[ft], bg[nt], acc[ft][nt]);
    asm volatile("s_waitcnt lgkmcnt(0)" ::: "memory");
    __builtin_amdgcn_s_barrier();  // raw: vmem prefetches stay in flight
  };

  for (int it2 = 0; it2 < KV_NIT; it2 += 2) {
    STEP(it2, krgA, vvA, krgB, vvB, 0);
    STEP(it2 + 1, krgB, vvB, krgA, vvA, 1);
  }

  // coalesced [f][n] stores: per instr, 16 lanes (lr) x 4B = 64B contiguous
  float* outb = kv_part + ((size_t)chunk * 32 + bh) * (FDIM * 68);
#pragma unroll
  for (int ft = 0; ft < 4; ++ft)
#pragma unroll
    for (int q = 0; q < 4; ++q) {
      int f = f0 + ft * 16 + lg * 4 + q;
#pragma unroll
      for (int nt = 0; nt < 4; ++nt)
        outb[(size_t)f * 68 + nt * 16 + lr] = acc[ft][nt][q];
      if (lr < 4) outb[(size_t)f * 68 + 64 + lr] = acc[ft][4][q];
    }
}

// ------- reduce NCHUNK partials [bh][f][n] -> kvT bf16 [bh][n=80][f-XOR-swizzled] -------
// kvT row n stores logical 16B-slot s at memory slot s ^ (n&7)  (involution).
__global__ __launch_bounds__(256) void kv_reduce(const float* __restrict__ part,
                                                 bf16_t* __restrict__ kvT) {
  int i = blockIdx.x * 256 + threadIdx.x;  // grid 2560: 557056 reduce + 98304 zero-fill
  if (i < KVP_CH) {
    int n = i % 68;
    int t = i / 68;  // bh*256 + f
    int f = t & 255, bh = t >> 8;
    float s = 0.0f;
#pragma unroll
    for (int c = 0; c < NCHUNK; ++c) s += part[(size_t)c * KVP_CH + i];
    int fs = ((((f >> 3) ^ (n & 7)) << 3) | (f & 7));
    kvT[((size_t)bh * 80 + n) * FDIM + fs] = (__bf16)s;
  } else {
    int j = i - KVP_CH;  // 32*12*256
    int f = j & 255;
    int t = j >> 8;  // bh*12 + (n-68)
    int n = 68 + t % 12, bh = t / 12;
    kvT[((size_t)bh * 80 + n) * FDIM + f] = (__bf16)0.0f;
  }
}

// ------- fused featq+readout: outp = (qf @ kv) / (qf . ksum + 1e-6), grid (M/64, NH) ------
// kvT[bh] (40KB, pre-swizzled) staged to LDS during qf-gen; B-fragments read from LDS.
__global__ __launch_bounds__(256) void attn_fused(const bf16_t* __restrict__ Qb,
                                                  const bf16_t* __restrict__ Wf,
                                                  const bf16_t* __restrict__ kvT,
                                                  bf16_t* __restrict__ outp) {
  __shared__ bf16_t qf_lds[64 * 264];
  __shared__ bf16_t kv_lds[80 * 256];
  int rb = blockIdx.x, h = blockIdx.y;
  int row0 = rb * 64;
  int bh = (row0 >> 13) * NH + h;  // SEQ = 8192 rows per batch
  int lane = threadIdx.x & 63, wid = threadIdx.x >> 6;
  int lr = lane & 15, lg = lane >> 4;
  int f0 = wid * 64;
  // stage kvT[bh] -> LDS (linear; swizzle already applied in global layout)
  const bf16_t* kvTb = kvT + (size_t)bh * 80 * FDIM;
#pragma unroll
  for (int i = 0; i < 10; ++i) {
    int sbase = wid * 640 + i * 64;  // 16B-slot index base (wave-uniform)
    gload_lds16(kvTb + (size_t)(sbase + lane) * 8, kv_lds + sbase * 8);
  }
  // qf-gen (hides staging latency)
  bfv8 qa[4][2], wfb[4][2];
#pragma unroll
  for (int t = 0; t < 4; ++t)
#pragma unroll
    for (int kk = 0; kk < 2; ++kk) {
      qa[t][kk] = *reinterpret_cast<const bfv8*>(Qb + (size_t)(row0 + t * 16 + lr) * DIM + h * HDIM + kk * 32 + lg * 8);
      wfb[t][kk] = *reinterpret_cast<const bfv8*>(Wf + (size_t)(f0 + t * 16 + lr) * HDIM + kk * 32 + lg * 8);
    }
  f32x4 cq[4][4] = {};
#pragma unroll
  for (int rt = 0; rt < 4; ++rt)
#pragma unroll
    for (int ft = 0; ft < 4; ++ft)
#pragma unroll
      for (int kk = 0; kk < 2; ++kk) cq[rt][ft] = mfma_bf16(qa[rt][kk], wfb[ft][kk], cq[rt][ft]);
#pragma unroll
  for (int rt = 0; rt < 4; ++rt)
#pragma unroll
    for (int ft = 0; ft < 4; ++ft)
#pragma unroll
      for (int q = 0; q < 4; ++q) {
        float x = cq[rt][ft][q];
        x = (x > 0.0f) ? (x + 1.0f) : __expf(x);
        qf_lds[(size_t)(rt * 16 + lg * 4 + q) * 264 + f0 + ft * 16 + lr] = (__bf16)x;
      }
  __syncthreads();  // drains staging vmcnt + qf_lds visible
  f32x4 acc[5] = {};
#pragma unroll
  for (int ks = 0; ks < 8; ++ks) {
    bfv8 a = *reinterpret_cast<const bfv8*>(&qf_lds[(size_t)(wid * 16 + lr) * 264 + ks * 32 + lg * 8]);
#pragma unroll
    for (int nt = 0; nt < 5; ++nt) {
      bfv8 bg = *reinterpret_cast<const bfv8*>(
          &kv_lds[(size_t)(nt * 16 + lr) * 256 + (((ks * 4 + lg) ^ (lr & 7)) * 8)]);
      acc[nt] = mfma_bf16(a, bg, acc[nt]);
    }
  }
  // normalize -> stage out tile in LDS (reuse qf_lds) -> coalesced 128B-row stores
  __syncthreads();  // all waves done reading qf_lds
#pragma unroll
  for (int q = 0; q < 4; ++q) {
    float nrm = __shfl(acc[4][q], (lane & 48)) + 1e-6f;
    int row = wid * 16 + lg * 4 + q;
#pragma unroll
    for (int nt = 0; nt < 4; ++nt)
      qf_lds[(size_t)row * 264 + nt * 16 + lr] = (__bf16)(acc[nt][q] / nrm);
  }
  __syncthreads();
#pragma unroll
  for (int rep = 0; rep < 2; ++rep) {
    int id = rep * 256 + threadIdx.x;
    int row = id >> 3, c8 = id & 7;
    bfv8 v = *reinterpret_cast<const bfv8*>(&qf_lds[(size_t)row * 264 + c8 * 8]);
    *reinterpret_cast<bfv8*>(&outp[(size_t)(row0 + row) * DIM + h * HDIM + c8 * 8]) = v;
  }
}

extern "C" void kernel_launch(void* const* d_in, const int* in_sizes, int n_in,
                              void* d_out, int out_size, void* d_ws, size_t ws_size,
                              hipStream_t stream) {
  const float* X  = (const float*)d_in[0];
  const float* Wq = (const float*)d_in[1];
  const float* Wk = (const float*)d_in[2];
  const float* Wv = (const float*)d_in[3];
  const float* Wo = (const float*)d_in[4];
  const float* Wf = (const float*)d_in[5];
  float* out = (float*)d_out;
  char* ws = (char*)d_ws;
  const size_t MB = 1ull << 20;
  if (ws_size < 75 * MB) return;

  // arena (75 MB) + d_out (64 MB) as scratch for K/V
  bf16_t* Xb  = (bf16_t*)(ws + 0 * MB);    // 32MB; dead after gemm_qkv
  bf16_t* W3  = (bf16_t*)(ws + 32 * MB);   // 6MB;  dead after gemm_qkv
  bf16_t* Qb  = (bf16_t*)(ws + 38 * MB);   // 32MB; live until attn_fused
  bf16_t* Wob = (bf16_t*)(ws + 70 * MB);   // 2MB;  live until gemm_final
  bf16_t* Wfb = (bf16_t*)(ws + 72 * MB);   // 32KB
  bf16_t* kvT = (bf16_t*)(ws + 73 * MB);   // 1.31MB
  float* kv_part = (float*)(ws + 0 * MB);  // 35.7MB over dead Xb+W3
  bf16_t* outp = (bf16_t*)(ws + 0 * MB);   // 32MB over dead kv_part
  bf16_t* Kb = (bf16_t*)d_out;             // 32MB scratch in d_out
  bf16_t* Vb = Kb + (size_t)MROWS * DIM;   // 32MB scratch in d_out

  cvt_all<<<20496, 256, 0, stream>>>(X, Wq, Wk, Wv, Wo, Wf, Xb, W3, Wob, Wfb);

  gemm_qkv<<<dim3(128, 8, 3), 256, 0, stream>>>(Xb, W3, Qb, Kb, Vb);
  kv_fused<<<dim3(NCHUNK, 32), 256, 0, stream>>>(Kb, Vb, Wfb, kv_part);
  kv_reduce<<<2560, 256, 0, stream>>>(kv_part, kvT);
  attn_fused<<<dim3(256, NH), 256, 0, stream>>>(Qb, Wfb, kvT, outp);
  gemm_final<<<dim3(128, 8), 256, 0, stream>>>(outp, Wob, out);
}